// Round 10
// baseline (278.333 us; speedup 1.0000x reference)
//
#include <hip/hip_runtime.h>
#include <hip/hip_fp16.h>
#include <math.h>

#define N_NODES 100000
#define N_EDGES 1600000

// ================= CSR build (by dst) =================
// count: rnk[i] = arrival rank of edge i within its dst (atomicAdd return),
// stored as u16 (max degree << 65536). 8 independent atomics in flight/thread.

__global__ void k_count(const int* __restrict__ dst, int* __restrict__ cnt,
                        unsigned short* __restrict__ rnk, int e) {
    int i = (blockIdx.x * blockDim.x + threadIdx.x) * 8;
    if (i + 8 <= e) {
        int4 dA = *(const int4*)(dst + i);
        int4 dB = *(const int4*)(dst + i + 4);
        int r0 = atomicAdd(&cnt[dA.x], 1);
        int r1 = atomicAdd(&cnt[dA.y], 1);
        int r2 = atomicAdd(&cnt[dA.z], 1);
        int r3 = atomicAdd(&cnt[dA.w], 1);
        int r4 = atomicAdd(&cnt[dB.x], 1);
        int r5 = atomicAdd(&cnt[dB.y], 1);
        int r6 = atomicAdd(&cnt[dB.z], 1);
        int r7 = atomicAdd(&cnt[dB.w], 1);
        int4 p;
        p.x = (r0 & 0xffff) | (r1 << 16);
        p.y = (r2 & 0xffff) | (r3 << 16);
        p.z = (r4 & 0xffff) | (r5 << 16);
        p.w = (r6 & 0xffff) | (r7 << 16);
        *(int4*)(rnk + i) = p;   // 16-B coalesced store of 8 u16 ranks
    } else {
        for (; i < e; ++i) rnk[i] = (unsigned short)atomicAdd(&cnt[dst[i]], 1);
    }
}

// scanA: per-block exclusive scan of 1024 ints (4/thread); block totals -> bsums.
// Also computes dinv = rsqrt(deg+1).
__global__ void k_scanA(const int* __restrict__ cnt, int* __restrict__ off,
                        int* __restrict__ bsums, float* __restrict__ dinv, int n) {
    __shared__ int sd[256];
    int t = threadIdx.x;
    int base = blockIdx.x * 1024 + t * 4;
    int e0 = (base + 0 < n) ? cnt[base + 0] : 0;
    int e1 = (base + 1 < n) ? cnt[base + 1] : 0;
    int e2 = (base + 2 < n) ? cnt[base + 2] : 0;
    int e3 = (base + 3 < n) ? cnt[base + 3] : 0;
    if (base + 0 < n) dinv[base + 0] = rsqrtf((float)e0 + 1.0f);
    if (base + 1 < n) dinv[base + 1] = rsqrtf((float)e1 + 1.0f);
    if (base + 2 < n) dinv[base + 2] = rsqrtf((float)e2 + 1.0f);
    if (base + 3 < n) dinv[base + 3] = rsqrtf((float)e3 + 1.0f);
    int s = e0 + e1 + e2 + e3;
    sd[t] = s;
    __syncthreads();
    for (int o = 1; o < 256; o <<= 1) {
        int v = (t >= o) ? sd[t - o] : 0;
        __syncthreads();
        sd[t] += v;
        __syncthreads();
    }
    int excl = sd[t] - s;
    if (base + 0 < n) off[base + 0] = excl;
    if (base + 1 < n) off[base + 1] = excl + e0;
    if (base + 2 < n) off[base + 2] = excl + e0 + e1;
    if (base + 3 < n) off[base + 3] = excl + e0 + e1 + e2;
    if (t == 0) bsums[blockIdx.x] = sd[255];
}

// scanC: every block redundantly scans bsums (nb<=128) in LDS, then applies the
// prefix to its 256 off entries.
__global__ void k_scanC(int* __restrict__ off, const int* __restrict__ bsums,
                        int nb, int n) {
    __shared__ int sd[128];
    int t = threadIdx.x;
    if (t < 128) sd[t] = (t < nb) ? bsums[t] : 0;
    __syncthreads();
    for (int o = 1; o < 128; o <<= 1) {
        int v = (t >= o && t < 128) ? sd[t - o] : 0;
        __syncthreads();
        if (t < 128) sd[t] += v;
        __syncthreads();
    }
    int i = blockIdx.x * 256 + t;
    if (i < n) {
        int b = i >> 10;
        int add = (b == 0) ? 0 : sd[b - 1];
        off[i] = off[i] + add;
    }
    if (blockIdx.x == 0 && t == 0) off[n] = sd[nb - 1];
}

// fill: atomic-free scatter, 8 edges/thread. pos = off[dst] + rnk.
__global__ void k_fill(const int* __restrict__ src, const int* __restrict__ dst,
                       const unsigned short* __restrict__ rnk,
                       const int* __restrict__ off, int* __restrict__ csr, int e) {
    int i = (blockIdx.x * blockDim.x + threadIdx.x) * 8;
    if (i + 8 <= e) {
        int4 sA = *(const int4*)(src + i), sB = *(const int4*)(src + i + 4);
        int4 dA = *(const int4*)(dst + i), dB = *(const int4*)(dst + i + 4);
        int4 rp = *(const int4*)(rnk + i);
        csr[off[dA.x] + (rp.x & 0xffff)] = sA.x;
        csr[off[dA.y] + ((unsigned)rp.x >> 16)] = sA.y;
        csr[off[dA.z] + (rp.y & 0xffff)] = sA.z;
        csr[off[dA.w] + ((unsigned)rp.y >> 16)] = sA.w;
        csr[off[dB.x] + (rp.z & 0xffff)] = sB.x;
        csr[off[dB.y] + ((unsigned)rp.z >> 16)] = sB.y;
        csr[off[dB.z] + (rp.w & 0xffff)] = sB.z;
        csr[off[dB.w] + ((unsigned)rp.w >> 16)] = sB.w;
    } else {
        for (; i < e; ++i) csr[off[dst[i]] + rnk[i]] = src[i];
    }
}

// ======== fold: xs[s][f] = x[s][f] * dinv[s] ========
__global__ void k_fold(const float* __restrict__ x, const float* __restrict__ dinv,
                       float* __restrict__ xs) {
    int t = blockIdx.x * blockDim.x + threadIdx.x;  // float4 index
    float4 v = ((const float4*)x)[t];
    float di = dinv[t >> 4];
    float4 o;
    o.x = v.x * di; o.y = v.y * di; o.z = v.z * di; o.w = v.w * di;
    ((float4*)xs)[t] = o;
}

// ======== Fused layer-1 agg + GEMM1 + relu + GEMM2 ========
// (unchanged from R9 — at the request-throughput wall; isolates other changes)

__global__ void k_agg1(
        const float* __restrict__ xs, const int* __restrict__ off,
        const int* __restrict__ csr, const float* __restrict__ dinv,
        const float* __restrict__ W1, const float* __restrict__ W2,
        const float* __restrict__ b1, __half* __restrict__ h2h, int n) {
    __shared__ float W1s[64 * 64];
    __shared__ float W2s[64 * 17];   // padded
    __shared__ float xsw[4][64];
    __shared__ float vsw[4][64];
    int tid = threadIdx.x;
    {
        const float4* W14 = (const float4*)W1;
        float4* W1s4 = (float4*)W1s;
#pragma unroll
        for (int i = 0; i < 4; ++i) W1s4[tid + 256 * i] = W14[tid + 256 * i];
        for (int i = tid; i < 64 * 16; i += 256) W2s[(i >> 4) * 17 + (i & 15)] = W2[i];
    }
    __syncthreads();  // only block-wide barrier

    int w = tid >> 6, lane = tid & 63;
    int f = lane;
    int G = lane >> 4;
    int c4 = lane & 15;
    float b1f = b1[f];

    int base = blockIdx.x * 16 + w * 4;
#pragma unroll 1
    for (int nn = 0; nn < 4; ++nn) {
        int d = base + nn;    // grid covers n exactly
        float dd = dinv[d];
        float a0 = xs[(size_t)d * 64 + f];   // self term (prefolded)
        float a1 = 0.f, a2 = 0.f, a3 = 0.f;
        int j = off[d], je = off[d + 1];
        int s0 = 0, s1 = 0, s2 = 0, s3 = 0;
        if (j + 4 <= je) { s0 = csr[j]; s1 = csr[j + 1]; s2 = csr[j + 2]; s3 = csr[j + 3]; }
        while (j + 4 <= je) {
            int t0 = s0, t1 = s1, t2 = s2, t3 = s3;
            if (j + 8 <= je) { t0 = csr[j + 4]; t1 = csr[j + 5]; t2 = csr[j + 6]; t3 = csr[j + 7]; }
            a0 += xs[(size_t)s0 * 64 + f];
            a1 += xs[(size_t)s1 * 64 + f];
            a2 += xs[(size_t)s2 * 64 + f];
            a3 += xs[(size_t)s3 * 64 + f];
            s0 = t0; s1 = t1; s2 = t2; s3 = t3;
            j += 4;
        }
        for (; j < je; ++j) {
            int s = csr[j];
            a0 += xs[(size_t)s * 64 + f];
        }
        xsw[w][f] = ((a0 + a1) + (a2 + a3)) * dd;   // same-wave producer
        // Phase B
        float p0 = b1f, p1 = 0.f, p2 = 0.f, p3 = 0.f;
        const float4* xw4 = (const float4*)xsw[w];
#pragma unroll
        for (int k4 = 0; k4 < 16; ++k4) {
            float4 xv = xw4[k4];
            p0 = fmaf(xv.x, W1s[(k4 * 4 + 0) * 64 + f], p0);
            p1 = fmaf(xv.y, W1s[(k4 * 4 + 1) * 64 + f], p1);
            p2 = fmaf(xv.z, W1s[(k4 * 4 + 2) * 64 + f], p2);
            p3 = fmaf(xv.w, W1s[(k4 * 4 + 3) * 64 + f], p3);
        }
        vsw[w][f] = fmaxf((p0 + p1) + (p2 + p3), 0.f);
        // Phase C
        float p = 0.f;
        const float4* vw4 = (const float4*)vsw[w];
#pragma unroll
        for (int kk4 = 0; kk4 < 4; ++kk4) {
            float4 vv = vw4[G * 4 + kk4];
            p = fmaf(vv.x, W2s[(G * 16 + kk4 * 4 + 0) * 17 + c4], p);
            p = fmaf(vv.y, W2s[(G * 16 + kk4 * 4 + 1) * 17 + c4], p);
            p = fmaf(vv.z, W2s[(G * 16 + kk4 * 4 + 2) * 17 + c4], p);
            p = fmaf(vv.w, W2s[(G * 16 + kk4 * 4 + 3) * 17 + c4], p);
        }
        p += __shfl_xor(p, 16);
        p += __shfl_xor(p, 32);
        if (G == 0) h2h[(size_t)d * 16 + c4] = __float2half(p * dd);
    }
}

// ======== Layer-2 aggregation + b2 + log_softmax ========
// 1 node/wave, 4 waves/block. lane = 16*g + c; depth 4 (16 edges in flight).
// h2h fp16 L2-resident: deep queues are L2-hits, no HBM amplification possible.

__global__ void k_agg2_lsm(
        const __half* __restrict__ h2h, const int* __restrict__ off,
        const int* __restrict__ csr, const float* __restrict__ dinv,
        const float* __restrict__ b2, float* __restrict__ y, int n) {
    int tid = threadIdx.x;
    int w = tid >> 6, lane = tid & 63, g = lane >> 4, c = lane & 15;
    int d = blockIdx.x * 4 + w;   // grid covers n exactly
    float dd = dinv[d];
    float acc0 = (g == 0) ? __half2float(h2h[(size_t)d * 16 + c]) : 0.f;  // self
    float acc1 = 0.f, acc2 = 0.f, acc3 = 0.f;
    int j = off[d], je = off[d + 1];
    for (; j + 16 <= je; j += 16) {
        int sA = csr[j + g], sB = csr[j + 4 + g];
        int sC = csr[j + 8 + g], sD = csr[j + 12 + g];
        acc0 += __half2float(h2h[(size_t)sA * 16 + c]);
        acc1 += __half2float(h2h[(size_t)sB * 16 + c]);
        acc2 += __half2float(h2h[(size_t)sC * 16 + c]);
        acc3 += __half2float(h2h[(size_t)sD * 16 + c]);
    }
    for (; j < je; j += 4) {         // rem 0..15, <=4 iterations
        if (j + g < je) {
            int s = csr[j + g];
            acc0 += __half2float(h2h[(size_t)s * 16 + c]);
        }
    }
    float acc = (acc0 + acc1) + (acc2 + acc3);
    acc += __shfl_xor(acc, 16);
    acc += __shfl_xor(acc, 32);
    float v = acc * dd + b2[c];
    float m = v;
#pragma unroll
    for (int o = 1; o < 16; o <<= 1) m = fmaxf(m, __shfl_xor(m, o));
    float ss = expf(v - m);
#pragma unroll
    for (int o = 1; o < 16; o <<= 1) ss += __shfl_xor(ss, o);
    float lse = logf(ss) + m;
    if (g == 0) y[(size_t)d * 16 + c] = v - lse;
}

// ================= launcher =================

extern "C" void kernel_launch(void* const* d_in, const int* in_sizes, int n_in,
                              void* d_out, int out_size, void* d_ws, size_t ws_size,
                              hipStream_t stream) {
    const float* x  = (const float*)d_in[0];
    const int*   ei = (const int*)d_in[1];          // [2, E] row-major
    const float* W1 = (const float*)d_in[2];
    const float* b1 = (const float*)d_in[3];
    const float* W2 = (const float*)d_in[4];
    const float* b2 = (const float*)d_in[5];
    float* y = (float*)d_out;

    const int n = N_NODES;
    const int e = N_EDGES;
    const int* src = ei;
    const int* dst = ei + e;

    // workspace layout (4-byte units); total ~40 MB
    float* ws = (float*)d_ws;
    int*            cnt   = (int*)ws;                    // n
    float*          dinv  = ws + 102400;                 // n
    int*            off   = (int*)(ws + 204800);         // n+1
    int*            bsums = (int*)(ws + 307200);         // <=128
    unsigned short* rnk   = (unsigned short*)(ws + 409600);  // e u16 (3.2MB)
    int*            csr   = (int*)(ws + 1209600);        // e
    float*          xs    = ws + 2809600;                // n*64 (25.6MB), 16B-aligned
    __half*         h2h   = (__half*)(ws + 9209600);     // n*16 halves (3.2MB)

    const int nb = (n + 1023) / 1024;                    // 98

    hipMemsetAsync(cnt, 0, (size_t)n * sizeof(int), stream);
    k_count<<<(e / 8 + 255) / 256, 256, 0, stream>>>(dst, cnt, rnk, e);
    k_scanA<<<nb, 256, 0, stream>>>(cnt, off, bsums, dinv, n);
    k_fold <<<n * 16 / 256, 256, 0, stream>>>(x, dinv, xs);          // 6250
    k_scanC<<<(n + 255) / 256, 256, 0, stream>>>(off, bsums, nb, n);
    k_fill <<<(e / 8 + 255) / 256, 256, 0, stream>>>(src, dst, rnk, off, csr, e);

    k_agg1    <<<n / 16, 256, 0, stream>>>(xs, off, csr, dinv, W1, W2, b1, h2h, n);  // 6250
    k_agg2_lsm<<<n / 4, 256, 0, stream>>>(h2h, off, csr, dinv, b2, y, n);            // 25000
}

// Round 11
// 267.123 us; speedup vs baseline: 1.0420x; 1.0420x over previous
//
#include <hip/hip_runtime.h>
#include <hip/hip_fp16.h>
#include <math.h>

#define N_NODES 100000
#define N_EDGES 1600000

// ================= CSR build (by dst) =================
// count: rnk[i] = arrival rank of edge i within its dst (atomicAdd return),
// stored as u16. 8 independent atomics in flight per thread.

__global__ void k_count(const int* __restrict__ dst, int* __restrict__ cnt,
                        unsigned short* __restrict__ rnk, int e) {
    int i = (blockIdx.x * blockDim.x + threadIdx.x) * 8;
    if (i + 8 <= e) {
        int4 dA = *(const int4*)(dst + i);
        int4 dB = *(const int4*)(dst + i + 4);
        int r0 = atomicAdd(&cnt[dA.x], 1);
        int r1 = atomicAdd(&cnt[dA.y], 1);
        int r2 = atomicAdd(&cnt[dA.z], 1);
        int r3 = atomicAdd(&cnt[dA.w], 1);
        int r4 = atomicAdd(&cnt[dB.x], 1);
        int r5 = atomicAdd(&cnt[dB.y], 1);
        int r6 = atomicAdd(&cnt[dB.z], 1);
        int r7 = atomicAdd(&cnt[dB.w], 1);
        int4 p;
        p.x = (r0 & 0xffff) | (r1 << 16);
        p.y = (r2 & 0xffff) | (r3 << 16);
        p.z = (r4 & 0xffff) | (r5 << 16);
        p.w = (r6 & 0xffff) | (r7 << 16);
        *(int4*)(rnk + i) = p;   // 16-B coalesced store of 8 u16 ranks
    } else {
        for (; i < e; ++i) rnk[i] = (unsigned short)atomicAdd(&cnt[dst[i]], 1);
    }
}

// scanA: per-block exclusive scan of 1024 ints (4/thread); block totals -> bsums.
// Also computes dinv = rsqrt(deg+1).
__global__ void k_scanA(const int* __restrict__ cnt, int* __restrict__ off,
                        int* __restrict__ bsums, float* __restrict__ dinv, int n) {
    __shared__ int sd[256];
    int t = threadIdx.x;
    int base = blockIdx.x * 1024 + t * 4;
    int e0 = (base + 0 < n) ? cnt[base + 0] : 0;
    int e1 = (base + 1 < n) ? cnt[base + 1] : 0;
    int e2 = (base + 2 < n) ? cnt[base + 2] : 0;
    int e3 = (base + 3 < n) ? cnt[base + 3] : 0;
    if (base + 0 < n) dinv[base + 0] = rsqrtf((float)e0 + 1.0f);
    if (base + 1 < n) dinv[base + 1] = rsqrtf((float)e1 + 1.0f);
    if (base + 2 < n) dinv[base + 2] = rsqrtf((float)e2 + 1.0f);
    if (base + 3 < n) dinv[base + 3] = rsqrtf((float)e3 + 1.0f);
    int s = e0 + e1 + e2 + e3;
    sd[t] = s;
    __syncthreads();
    for (int o = 1; o < 256; o <<= 1) {
        int v = (t >= o) ? sd[t - o] : 0;
        __syncthreads();
        sd[t] += v;
        __syncthreads();
    }
    int excl = sd[t] - s;
    if (base + 0 < n) off[base + 0] = excl;
    if (base + 1 < n) off[base + 1] = excl + e0;
    if (base + 2 < n) off[base + 2] = excl + e0 + e1;
    if (base + 3 < n) off[base + 3] = excl + e0 + e1 + e2;
    if (t == 0) bsums[blockIdx.x] = sd[255];
}

// scanC: every block redundantly scans bsums (nb<=128) in LDS, then applies the
// prefix to its 256 off entries.
__global__ void k_scanC(int* __restrict__ off, const int* __restrict__ bsums,
                        int nb, int n) {
    __shared__ int sd[128];
    int t = threadIdx.x;
    if (t < 128) sd[t] = (t < nb) ? bsums[t] : 0;
    __syncthreads();
    for (int o = 1; o < 128; o <<= 1) {
        int v = (t >= o && t < 128) ? sd[t - o] : 0;
        __syncthreads();
        if (t < 128) sd[t] += v;
        __syncthreads();
    }
    int i = blockIdx.x * 256 + t;
    if (i < n) {
        int b = i >> 10;
        int add = (b == 0) ? 0 : sd[b - 1];
        off[i] = off[i] + add;
    }
    if (blockIdx.x == 0 && t == 0) off[n] = sd[nb - 1];
}

// ======== fused fill + fold ========
// Blocks [0, FB): atomic-free CSR scatter (latency-bound).
// Blocks [FB, FB+6250): xs[s][f] = x[s][f] * rsqrt(cnt[s]+1) (BW-bound stream).
// The two halves use complementary pipes and overlap within one dispatch.

#define FILL_BLOCKS 782   // ceil(E/8/256)

__global__ void k_fill_fold(const int* __restrict__ src, const int* __restrict__ dst,
                            const unsigned short* __restrict__ rnk,
                            const int* __restrict__ off, int* __restrict__ csr,
                            const float* __restrict__ x, const int* __restrict__ cnt,
                            float* __restrict__ xs, int e) {
    int bid = blockIdx.x;
    if (bid < FILL_BLOCKS) {
        int i = (bid * blockDim.x + threadIdx.x) * 8;
        if (i + 8 <= e) {
            int4 sA = *(const int4*)(src + i), sB = *(const int4*)(src + i + 4);
            int4 dA = *(const int4*)(dst + i), dB = *(const int4*)(dst + i + 4);
            int4 rp = *(const int4*)(rnk + i);
            csr[off[dA.x] + (rp.x & 0xffff)] = sA.x;
            csr[off[dA.y] + ((unsigned)rp.x >> 16)] = sA.y;
            csr[off[dA.z] + (rp.y & 0xffff)] = sA.z;
            csr[off[dA.w] + ((unsigned)rp.y >> 16)] = sA.w;
            csr[off[dB.x] + (rp.z & 0xffff)] = sB.x;
            csr[off[dB.y] + ((unsigned)rp.z >> 16)] = sB.y;
            csr[off[dB.z] + (rp.w & 0xffff)] = sB.z;
            csr[off[dB.w] + ((unsigned)rp.w >> 16)] = sB.w;
        } else {
            for (; i < e; ++i) csr[off[dst[i]] + rnk[i]] = src[i];
        }
    } else {
        int t = (bid - FILL_BLOCKS) * blockDim.x + threadIdx.x;  // float4 index
        float4 v = ((const float4*)x)[t];
        float di = rsqrtf((float)cnt[t >> 4] + 1.0f);   // independent of scanA
        float4 o;
        o.x = v.x * di; o.y = v.y * di; o.z = v.z * di; o.w = v.w * di;
        ((float4*)xs)[t] = o;
    }
}

// ======== Fused layer-1 agg + GEMM1 + relu + GEMM2 ========
// (unchanged — at the L2-miss request-throughput wall)

__global__ void k_agg1(
        const float* __restrict__ xs, const int* __restrict__ off,
        const int* __restrict__ csr, const float* __restrict__ dinv,
        const float* __restrict__ W1, const float* __restrict__ W2,
        const float* __restrict__ b1, __half* __restrict__ h2h, int n) {
    __shared__ float W1s[64 * 64];
    __shared__ float W2s[64 * 17];   // padded
    __shared__ float xsw[4][64];
    __shared__ float vsw[4][64];
    int tid = threadIdx.x;
    {
        const float4* W14 = (const float4*)W1;
        float4* W1s4 = (float4*)W1s;
#pragma unroll
        for (int i = 0; i < 4; ++i) W1s4[tid + 256 * i] = W14[tid + 256 * i];
        for (int i = tid; i < 64 * 16; i += 256) W2s[(i >> 4) * 17 + (i & 15)] = W2[i];
    }
    __syncthreads();  // only block-wide barrier

    int w = tid >> 6, lane = tid & 63;
    int f = lane;
    int G = lane >> 4;
    int c4 = lane & 15;
    float b1f = b1[f];

    int base = blockIdx.x * 16 + w * 4;
#pragma unroll 1
    for (int nn = 0; nn < 4; ++nn) {
        int d = base + nn;    // grid covers n exactly
        float dd = dinv[d];
        float a0 = xs[(size_t)d * 64 + f];   // self term (prefolded)
        float a1 = 0.f, a2 = 0.f, a3 = 0.f;
        int j = off[d], je = off[d + 1];
        int s0 = 0, s1 = 0, s2 = 0, s3 = 0;
        if (j + 4 <= je) { s0 = csr[j]; s1 = csr[j + 1]; s2 = csr[j + 2]; s3 = csr[j + 3]; }
        while (j + 4 <= je) {
            int t0 = s0, t1 = s1, t2 = s2, t3 = s3;
            if (j + 8 <= je) { t0 = csr[j + 4]; t1 = csr[j + 5]; t2 = csr[j + 6]; t3 = csr[j + 7]; }
            a0 += xs[(size_t)s0 * 64 + f];
            a1 += xs[(size_t)s1 * 64 + f];
            a2 += xs[(size_t)s2 * 64 + f];
            a3 += xs[(size_t)s3 * 64 + f];
            s0 = t0; s1 = t1; s2 = t2; s3 = t3;
            j += 4;
        }
        for (; j < je; ++j) {
            int s = csr[j];
            a0 += xs[(size_t)s * 64 + f];
        }
        xsw[w][f] = ((a0 + a1) + (a2 + a3)) * dd;   // same-wave producer
        // Phase B
        float p0 = b1f, p1 = 0.f, p2 = 0.f, p3 = 0.f;
        const float4* xw4 = (const float4*)xsw[w];
#pragma unroll
        for (int k4 = 0; k4 < 16; ++k4) {
            float4 xv = xw4[k4];
            p0 = fmaf(xv.x, W1s[(k4 * 4 + 0) * 64 + f], p0);
            p1 = fmaf(xv.y, W1s[(k4 * 4 + 1) * 64 + f], p1);
            p2 = fmaf(xv.z, W1s[(k4 * 4 + 2) * 64 + f], p2);
            p3 = fmaf(xv.w, W1s[(k4 * 4 + 3) * 64 + f], p3);
        }
        vsw[w][f] = fmaxf((p0 + p1) + (p2 + p3), 0.f);
        // Phase C
        float p = 0.f;
        const float4* vw4 = (const float4*)vsw[w];
#pragma unroll
        for (int kk4 = 0; kk4 < 4; ++kk4) {
            float4 vv = vw4[G * 4 + kk4];
            p = fmaf(vv.x, W2s[(G * 16 + kk4 * 4 + 0) * 17 + c4], p);
            p = fmaf(vv.y, W2s[(G * 16 + kk4 * 4 + 1) * 17 + c4], p);
            p = fmaf(vv.z, W2s[(G * 16 + kk4 * 4 + 2) * 17 + c4], p);
            p = fmaf(vv.w, W2s[(G * 16 + kk4 * 4 + 3) * 17 + c4], p);
        }
        p += __shfl_xor(p, 16);
        p += __shfl_xor(p, 32);
        if (G == 0) h2h[(size_t)d * 16 + c4] = __float2half(p * dd);
    }
}

// ======== Layer-2 aggregation + b2 + log_softmax (half2-wide) ========
// 1 node/wave, 4 waves/block. lane = 8*g + c2: c2 = half2 column (2 feats),
// g = edge slot 0..7 -> 8 edges per wave-instruction. Depth 2 = 16 in flight.

__global__ void k_agg2_lsm(
        const __half* __restrict__ h2h, const int* __restrict__ off,
        const int* __restrict__ csr, const float* __restrict__ dinv,
        const float* __restrict__ b2, float* __restrict__ y, int n) {
    int tid = threadIdx.x;
    int w = tid >> 6, lane = tid & 63, g = lane >> 3, c2 = lane & 7;
    int d = blockIdx.x * 4 + w;   // grid covers n exactly
    const __half2* h2 = (const __half2*)h2h;
    float dd = dinv[d];
    float2 sv = __half22float2(h2[(size_t)d * 8 + c2]);
    float ax0 = (g == 0) ? sv.x : 0.f;
    float ay0 = (g == 0) ? sv.y : 0.f;
    float ax1 = 0.f, ay1 = 0.f;
    int j = off[d], je = off[d + 1];
    for (; j + 16 <= je; j += 16) {
        int sA = csr[j + g], sB = csr[j + 8 + g];
        float2 vA = __half22float2(h2[(size_t)sA * 8 + c2]);
        float2 vB = __half22float2(h2[(size_t)sB * 8 + c2]);
        ax0 += vA.x; ay0 += vA.y;
        ax1 += vB.x; ay1 += vB.y;
    }
    for (; j < je; j += 8) {          // rem 0..15, <=2 iterations
        if (j + g < je) {
            int s = csr[j + g];
            float2 v = __half22float2(h2[(size_t)s * 8 + c2]);
            ax0 += v.x; ay0 += v.y;
        }
    }
    float ax = ax0 + ax1, ay = ay0 + ay1;
    ax += __shfl_xor(ax, 8);  ax += __shfl_xor(ax, 16); ax += __shfl_xor(ax, 32);
    ay += __shfl_xor(ay, 8);  ay += __shfl_xor(ay, 16); ay += __shfl_xor(ay, 32);
    float vx = ax * dd + b2[c2 * 2 + 0];
    float vy = ay * dd + b2[c2 * 2 + 1];
    // log_softmax over 16 feats = 8 lanes x 2 (replicated per g group)
    float m = fmaxf(vx, vy);
    m = fmaxf(m, __shfl_xor(m, 1));
    m = fmaxf(m, __shfl_xor(m, 2));
    m = fmaxf(m, __shfl_xor(m, 4));
    float ss = expf(vx - m) + expf(vy - m);
    ss += __shfl_xor(ss, 1);
    ss += __shfl_xor(ss, 2);
    ss += __shfl_xor(ss, 4);
    float lse = logf(ss) + m;
    if (g == 0) {
        float2 o; o.x = vx - lse; o.y = vy - lse;
        ((float2*)y)[(size_t)d * 8 + c2] = o;   // coalesced 64B per node
    }
}

// ================= launcher =================

extern "C" void kernel_launch(void* const* d_in, const int* in_sizes, int n_in,
                              void* d_out, int out_size, void* d_ws, size_t ws_size,
                              hipStream_t stream) {
    const float* x  = (const float*)d_in[0];
    const int*   ei = (const int*)d_in[1];          // [2, E] row-major
    const float* W1 = (const float*)d_in[2];
    const float* b1 = (const float*)d_in[3];
    const float* W2 = (const float*)d_in[4];
    const float* b2 = (const float*)d_in[5];
    float* y = (float*)d_out;

    const int n = N_NODES;
    const int e = N_EDGES;
    const int* src = ei;
    const int* dst = ei + e;

    // workspace layout (4-byte units); total ~40 MB
    float* ws = (float*)d_ws;
    int*            cnt   = (int*)ws;                    // n
    float*          dinv  = ws + 102400;                 // n
    int*            off   = (int*)(ws + 204800);         // n+1
    int*            bsums = (int*)(ws + 307200);         // <=128
    unsigned short* rnk   = (unsigned short*)(ws + 409600);  // e u16 (3.2MB)
    int*            csr   = (int*)(ws + 1209600);        // e
    float*          xs    = ws + 2809600;                // n*64 (25.6MB), 16B-aligned
    __half*         h2h   = (__half*)(ws + 9209600);     // n*16 halves (3.2MB)

    const int nb = (n + 1023) / 1024;                    // 98

    hipMemsetAsync(cnt, 0, (size_t)n * sizeof(int), stream);
    k_count<<<(e / 8 + 255) / 256, 256, 0, stream>>>(dst, cnt, rnk, e);
    k_scanA<<<nb, 256, 0, stream>>>(cnt, off, bsums, dinv, n);
    k_scanC<<<(n + 255) / 256, 256, 0, stream>>>(off, bsums, nb, n);
    k_fill_fold<<<FILL_BLOCKS + n * 16 / 256, 256, 0, stream>>>(
        src, dst, rnk, off, csr, x, cnt, xs, e);                     // 782 + 6250
    k_agg1    <<<n / 16, 256, 0, stream>>>(xs, off, csr, dinv, W1, W2, b1, h2h, n);  // 6250
    k_agg2_lsm<<<n / 4, 256, 0, stream>>>(h2h, off, csr, dinv, b2, y, n);            // 25000
}

// Round 12
// 265.156 us; speedup vs baseline: 1.0497x; 1.0074x over previous
//
#include <hip/hip_runtime.h>
#include <hip/hip_fp16.h>
#include <math.h>

#define N_NODES 100000
#define N_EDGES 1600000

// ================= CSR build (by dst) =================
// count: rnk[i] = arrival rank of edge i within its dst (atomicAdd return),
// stored as u16. 2 edges/thread -> 3125 blocks -> max resident waves, max
// in-flight atomics (concurrency-limited regime, not contention).

__global__ void k_count(const int* __restrict__ dst, int* __restrict__ cnt,
                        unsigned short* __restrict__ rnk, int e) {
    int i = (blockIdx.x * blockDim.x + threadIdx.x) * 2;
    if (i + 2 <= e) {
        int2 d2 = *(const int2*)(dst + i);
        int r0 = atomicAdd(&cnt[d2.x], 1);
        int r1 = atomicAdd(&cnt[d2.y], 1);
        *(unsigned*)(rnk + i) = (unsigned)(r0 & 0xffff) | ((unsigned)r1 << 16);
    } else {
        for (; i < e; ++i) rnk[i] = (unsigned short)atomicAdd(&cnt[dst[i]], 1);
    }
}

// scanA: per-block exclusive scan of 1024 ints (4/thread); block totals -> bsums.
// Also computes dinv = rsqrt(deg+1).
__global__ void k_scanA(const int* __restrict__ cnt, int* __restrict__ off,
                        int* __restrict__ bsums, float* __restrict__ dinv, int n) {
    __shared__ int sd[256];
    int t = threadIdx.x;
    int base = blockIdx.x * 1024 + t * 4;
    int e0 = (base + 0 < n) ? cnt[base + 0] : 0;
    int e1 = (base + 1 < n) ? cnt[base + 1] : 0;
    int e2 = (base + 2 < n) ? cnt[base + 2] : 0;
    int e3 = (base + 3 < n) ? cnt[base + 3] : 0;
    if (base + 0 < n) dinv[base + 0] = rsqrtf((float)e0 + 1.0f);
    if (base + 1 < n) dinv[base + 1] = rsqrtf((float)e1 + 1.0f);
    if (base + 2 < n) dinv[base + 2] = rsqrtf((float)e2 + 1.0f);
    if (base + 3 < n) dinv[base + 3] = rsqrtf((float)e3 + 1.0f);
    int s = e0 + e1 + e2 + e3;
    sd[t] = s;
    __syncthreads();
    for (int o = 1; o < 256; o <<= 1) {
        int v = (t >= o) ? sd[t - o] : 0;
        __syncthreads();
        sd[t] += v;
        __syncthreads();
    }
    int excl = sd[t] - s;
    if (base + 0 < n) off[base + 0] = excl;
    if (base + 1 < n) off[base + 1] = excl + e0;
    if (base + 2 < n) off[base + 2] = excl + e0 + e1;
    if (base + 3 < n) off[base + 3] = excl + e0 + e1 + e2;
    if (t == 0) bsums[blockIdx.x] = sd[255];
}

// scanC: every block redundantly scans bsums (nb<=128) in LDS, then applies the
// prefix to its 256 off entries.
__global__ void k_scanC(int* __restrict__ off, const int* __restrict__ bsums,
                        int nb, int n) {
    __shared__ int sd[128];
    int t = threadIdx.x;
    if (t < 128) sd[t] = (t < nb) ? bsums[t] : 0;
    __syncthreads();
    for (int o = 1; o < 128; o <<= 1) {
        int v = (t >= o && t < 128) ? sd[t - o] : 0;
        __syncthreads();
        if (t < 128) sd[t] += v;
        __syncthreads();
    }
    int i = blockIdx.x * 256 + t;
    if (i < n) {
        int b = i >> 10;
        int add = (b == 0) ? 0 : sd[b - 1];
        off[i] = off[i] + add;
    }
    if (blockIdx.x == 0 && t == 0) off[n] = sd[nb - 1];
}

// ======== fused fill + fold ========
// Blocks [0, FB): atomic-free CSR scatter (latency-bound).
// Blocks [FB, FB+6250): xs[s][f] = x[s][f] * rsqrt(cnt[s]+1) (BW-bound stream).

#define FILL_BLOCKS 782   // ceil(E/8/256)

__global__ void k_fill_fold(const int* __restrict__ src, const int* __restrict__ dst,
                            const unsigned short* __restrict__ rnk,
                            const int* __restrict__ off, int* __restrict__ csr,
                            const float* __restrict__ x, const int* __restrict__ cnt,
                            float* __restrict__ xs, int e) {
    int bid = blockIdx.x;
    if (bid < FILL_BLOCKS) {
        int i = (bid * blockDim.x + threadIdx.x) * 8;
        if (i + 8 <= e) {
            int4 sA = *(const int4*)(src + i), sB = *(const int4*)(src + i + 4);
            int4 dA = *(const int4*)(dst + i), dB = *(const int4*)(dst + i + 4);
            int4 rp = *(const int4*)(rnk + i);
            csr[off[dA.x] + (rp.x & 0xffff)] = sA.x;
            csr[off[dA.y] + ((unsigned)rp.x >> 16)] = sA.y;
            csr[off[dA.z] + (rp.y & 0xffff)] = sA.z;
            csr[off[dA.w] + ((unsigned)rp.y >> 16)] = sA.w;
            csr[off[dB.x] + (rp.z & 0xffff)] = sB.x;
            csr[off[dB.y] + ((unsigned)rp.z >> 16)] = sB.y;
            csr[off[dB.z] + (rp.w & 0xffff)] = sB.z;
            csr[off[dB.w] + ((unsigned)rp.w >> 16)] = sB.w;
        } else {
            for (; i < e; ++i) csr[off[dst[i]] + rnk[i]] = src[i];
        }
    } else {
        int t = (bid - FILL_BLOCKS) * blockDim.x + threadIdx.x;  // float4 index
        float4 v = ((const float4*)x)[t];
        float di = rsqrtf((float)cnt[t >> 4] + 1.0f);   // independent of scanA
        float4 o;
        o.x = v.x * di; o.y = v.y * di; o.z = v.z * di; o.w = v.w * di;
        ((float4*)xs)[t] = o;
    }
}

// ======== Fused layer-1 agg + GEMM1 + relu + GEMM2 ========
// (unchanged — at the L2-miss request-throughput wall)

__global__ void k_agg1(
        const float* __restrict__ xs, const int* __restrict__ off,
        const int* __restrict__ csr, const float* __restrict__ dinv,
        const float* __restrict__ W1, const float* __restrict__ W2,
        const float* __restrict__ b1, __half* __restrict__ h2h, int n) {
    __shared__ float W1s[64 * 64];
    __shared__ float W2s[64 * 17];   // padded
    __shared__ float xsw[4][64];
    __shared__ float vsw[4][64];
    int tid = threadIdx.x;
    {
        const float4* W14 = (const float4*)W1;
        float4* W1s4 = (float4*)W1s;
#pragma unroll
        for (int i = 0; i < 4; ++i) W1s4[tid + 256 * i] = W14[tid + 256 * i];
        for (int i = tid; i < 64 * 16; i += 256) W2s[(i >> 4) * 17 + (i & 15)] = W2[i];
    }
    __syncthreads();  // only block-wide barrier

    int w = tid >> 6, lane = tid & 63;
    int f = lane;
    int G = lane >> 4;
    int c4 = lane & 15;
    float b1f = b1[f];

    int base = blockIdx.x * 16 + w * 4;
#pragma unroll 1
    for (int nn = 0; nn < 4; ++nn) {
        int d = base + nn;    // grid covers n exactly
        float dd = dinv[d];
        float a0 = xs[(size_t)d * 64 + f];   // self term (prefolded)
        float a1 = 0.f, a2 = 0.f, a3 = 0.f;
        int j = off[d], je = off[d + 1];
        int s0 = 0, s1 = 0, s2 = 0, s3 = 0;
        if (j + 4 <= je) { s0 = csr[j]; s1 = csr[j + 1]; s2 = csr[j + 2]; s3 = csr[j + 3]; }
        while (j + 4 <= je) {
            int t0 = s0, t1 = s1, t2 = s2, t3 = s3;
            if (j + 8 <= je) { t0 = csr[j + 4]; t1 = csr[j + 5]; t2 = csr[j + 6]; t3 = csr[j + 7]; }
            a0 += xs[(size_t)s0 * 64 + f];
            a1 += xs[(size_t)s1 * 64 + f];
            a2 += xs[(size_t)s2 * 64 + f];
            a3 += xs[(size_t)s3 * 64 + f];
            s0 = t0; s1 = t1; s2 = t2; s3 = t3;
            j += 4;
        }
        for (; j < je; ++j) {
            int s = csr[j];
            a0 += xs[(size_t)s * 64 + f];
        }
        xsw[w][f] = ((a0 + a1) + (a2 + a3)) * dd;   // same-wave producer
        // Phase B
        float p0 = b1f, p1 = 0.f, p2 = 0.f, p3 = 0.f;
        const float4* xw4 = (const float4*)xsw[w];
#pragma unroll
        for (int k4 = 0; k4 < 16; ++k4) {
            float4 xv = xw4[k4];
            p0 = fmaf(xv.x, W1s[(k4 * 4 + 0) * 64 + f], p0);
            p1 = fmaf(xv.y, W1s[(k4 * 4 + 1) * 64 + f], p1);
            p2 = fmaf(xv.z, W1s[(k4 * 4 + 2) * 64 + f], p2);
            p3 = fmaf(xv.w, W1s[(k4 * 4 + 3) * 64 + f], p3);
        }
        vsw[w][f] = fmaxf((p0 + p1) + (p2 + p3), 0.f);
        // Phase C
        float p = 0.f;
        const float4* vw4 = (const float4*)vsw[w];
#pragma unroll
        for (int kk4 = 0; kk4 < 4; ++kk4) {
            float4 vv = vw4[G * 4 + kk4];
            p = fmaf(vv.x, W2s[(G * 16 + kk4 * 4 + 0) * 17 + c4], p);
            p = fmaf(vv.y, W2s[(G * 16 + kk4 * 4 + 1) * 17 + c4], p);
            p = fmaf(vv.z, W2s[(G * 16 + kk4 * 4 + 2) * 17 + c4], p);
            p = fmaf(vv.w, W2s[(G * 16 + kk4 * 4 + 3) * 17 + c4], p);
        }
        p += __shfl_xor(p, 16);
        p += __shfl_xor(p, 32);
        if (G == 0) h2h[(size_t)d * 16 + c4] = __float2half(p * dd);
    }
}

// ======== Layer-2 aggregation + b2 + log_softmax (half2-wide) ========
// (unchanged from R11)

__global__ void k_agg2_lsm(
        const __half* __restrict__ h2h, const int* __restrict__ off,
        const int* __restrict__ csr, const float* __restrict__ dinv,
        const float* __restrict__ b2, float* __restrict__ y, int n) {
    int tid = threadIdx.x;
    int w = tid >> 6, lane = tid & 63, g = lane >> 3, c2 = lane & 7;
    int d = blockIdx.x * 4 + w;   // grid covers n exactly
    const __half2* h2 = (const __half2*)h2h;
    float dd = dinv[d];
    float2 sv = __half22float2(h2[(size_t)d * 8 + c2]);
    float ax0 = (g == 0) ? sv.x : 0.f;
    float ay0 = (g == 0) ? sv.y : 0.f;
    float ax1 = 0.f, ay1 = 0.f;
    int j = off[d], je = off[d + 1];
    for (; j + 16 <= je; j += 16) {
        int sA = csr[j + g], sB = csr[j + 8 + g];
        float2 vA = __half22float2(h2[(size_t)sA * 8 + c2]);
        float2 vB = __half22float2(h2[(size_t)sB * 8 + c2]);
        ax0 += vA.x; ay0 += vA.y;
        ax1 += vB.x; ay1 += vB.y;
    }
    for (; j < je; j += 8) {          // rem 0..15, <=2 iterations
        if (j + g < je) {
            int s = csr[j + g];
            float2 v = __half22float2(h2[(size_t)s * 8 + c2]);
            ax0 += v.x; ay0 += v.y;
        }
    }
    float ax = ax0 + ax1, ay = ay0 + ay1;
    ax += __shfl_xor(ax, 8);  ax += __shfl_xor(ax, 16); ax += __shfl_xor(ax, 32);
    ay += __shfl_xor(ay, 8);  ay += __shfl_xor(ay, 16); ay += __shfl_xor(ay, 32);
    float vx = ax * dd + b2[c2 * 2 + 0];
    float vy = ay * dd + b2[c2 * 2 + 1];
    float m = fmaxf(vx, vy);
    m = fmaxf(m, __shfl_xor(m, 1));
    m = fmaxf(m, __shfl_xor(m, 2));
    m = fmaxf(m, __shfl_xor(m, 4));
    float ss = expf(vx - m) + expf(vy - m);
    ss += __shfl_xor(ss, 1);
    ss += __shfl_xor(ss, 2);
    ss += __shfl_xor(ss, 4);
    float lse = logf(ss) + m;
    if (g == 0) {
        float2 o; o.x = vx - lse; o.y = vy - lse;
        ((float2*)y)[(size_t)d * 8 + c2] = o;   // coalesced 64B per node
    }
}

// ================= launcher =================

extern "C" void kernel_launch(void* const* d_in, const int* in_sizes, int n_in,
                              void* d_out, int out_size, void* d_ws, size_t ws_size,
                              hipStream_t stream) {
    const float* x  = (const float*)d_in[0];
    const int*   ei = (const int*)d_in[1];          // [2, E] row-major
    const float* W1 = (const float*)d_in[2];
    const float* b1 = (const float*)d_in[3];
    const float* W2 = (const float*)d_in[4];
    const float* b2 = (const float*)d_in[5];
    float* y = (float*)d_out;

    const int n = N_NODES;
    const int e = N_EDGES;
    const int* src = ei;
    const int* dst = ei + e;

    // workspace layout (4-byte units); total ~40 MB
    float* ws = (float*)d_ws;
    int*            cnt   = (int*)ws;                    // n
    float*          dinv  = ws + 102400;                 // n
    int*            off   = (int*)(ws + 204800);         // n+1
    int*            bsums = (int*)(ws + 307200);         // <=128
    unsigned short* rnk   = (unsigned short*)(ws + 409600);  // e u16 (3.2MB)
    int*            csr   = (int*)(ws + 1209600);        // e
    float*          xs    = ws + 2809600;                // n*64 (25.6MB), 16B-aligned
    __half*         h2h   = (__half*)(ws + 9209600);     // n*16 halves (3.2MB)

    const int nb = (n + 1023) / 1024;                    // 98

    hipMemsetAsync(cnt, 0, (size_t)n * sizeof(int), stream);
    k_count<<<(e / 2 + 255) / 256, 256, 0, stream>>>(dst, cnt, rnk, e);   // 3125 blocks
    k_scanA<<<nb, 256, 0, stream>>>(cnt, off, bsums, dinv, n);
    k_scanC<<<(n + 255) / 256, 256, 0, stream>>>(off, bsums, nb, n);
    k_fill_fold<<<FILL_BLOCKS + n * 16 / 256, 256, 0, stream>>>(
        src, dst, rnk, off, csr, x, cnt, xs, e);                     // 782 + 6250
    k_agg1    <<<n / 16, 256, 0, stream>>>(xs, off, csr, dinv, W1, W2, b1, h2h, n);  // 6250
    k_agg2_lsm<<<n / 4, 256, 0, stream>>>(h2h, off, csr, dinv, b2, y, n);            // 25000
}